// Round 1
// baseline (1431.955 us; speedup 1.0000x reference)
//
#include <hip/hip_runtime.h>

#define N_ 32
#define C_ 512
#define T_ 2048
#define H_ 2
#define K_ 512
#define D_ 256
#define TT 32            // t-tile per block
#define KC 128           // codes per LDS chunk
#define DT 64            // dims per LDS chunk
#define NBINS (K_ * K_)  // 262144
#define XS 516           // x LDS row stride (floats), 16B-aligned rows, conflict-light writes

// ---------------- kernel 1: codebook squared norms ----------------
__global__ void cnorm_k(const float* __restrict__ cb, float* __restrict__ cnorm) {
    int id = blockIdx.x;            // 0..1023  (h*512 + k)
    int lane = threadIdx.x;         // 64 threads
    const float* p = cb + (size_t)id * D_;
    float s = 0.f;
    for (int i = lane; i < D_; i += 64) { float v = p[i]; s += v * v; }
    for (int off = 32; off; off >>= 1) s += __shfl_down(s, off, 64);
    if (lane == 0) cnorm[id] = s;
}

// ---------------- kernel 2: fused distance/argmin/gather/loss ----------------
__global__ __launch_bounds__(256) void vq_main(
    const float* __restrict__ x, const float* __restrict__ cb,
    const float* __restrict__ cnorm, float* __restrict__ out,
    int* __restrict__ counts, float* __restrict__ commit)
{
    __shared__ float xs[TT * XS];        // 66,048 B : x[t][c], c contiguous
    __shared__ float cbs[KC * DT];       // 32,768 B : code-major, XOR-swizzled fp4 groups
    __shared__ float rminv[TT][33];      // 4,224 B
    __shared__ int   rmink[TT][33];      // 4,224 B
    __shared__ int   idx_sh[TT][H_];
    __shared__ float wred[4];

    const int tid = threadIdx.x;
    const int n  = blockIdx.y;
    const int t0 = blockIdx.x * TT;

    // ---- stage x tile (transpose [C][Ttile] -> [Ttile][C]) ----
    {
        const int tt = tid & 31;
        int c = tid >> 5;
        const float* xp = x + (size_t)n * C_ * T_ + t0 + tt;
        #pragma unroll 8
        for (int i = 0; i < C_ / 8; ++i, c += 8)
            xs[tt * XS + c] = xp[(size_t)c * T_];
    }

    const int kgrp = tid & 31;   // 32 k-groups, 4 strided codes each (kgrp + 32*ki)
    const int tgrp = tid >> 5;   // 8 t-groups, 4 t each

    // ---- distance + argmin per head ----
    for (int h = 0; h < H_; ++h) {
        float minv[4]; int mink[4];
        #pragma unroll
        for (int ti = 0; ti < 4; ++ti) { minv[ti] = 1e30f; mink[ti] = 0; }

        for (int kc = 0; kc < K_ / KC; ++kc) {
            const int k0 = kc * KC;
            float acc[4][4];
            #pragma unroll
            for (int ti = 0; ti < 4; ++ti)
                #pragma unroll
                for (int ki = 0; ki < 4; ++ki) acc[ti][ki] = 0.f;

            for (int ddt = 0; ddt < D_ / DT; ++ddt) {
                const int dd0 = ddt * DT;
                __syncthreads();   // protect cbs (and first iter: xs) before restage
                // stage cbs[code][dd], XOR-swizzled float4 groups, b128 writes
                {
                    const int i = tid & 15;        // float4 group within DT
                    const int j0 = tid >> 4;       // code row
                    #pragma unroll
                    for (int it = 0; it < 8; ++it) {
                        const int j = j0 + (it << 4);
                        const float4 v = *(const float4*)&cb[((size_t)(h * K_ + k0 + j)) * D_ + dd0 + 4 * i];
                        const int g = i ^ (j & 7);
                        *(float4*)&cbs[j * DT + 4 * g] = v;
                    }
                }
                __syncthreads();
                // register-blocked 4t x 4k FMA
                #pragma unroll 4
                for (int dd4 = 0; dd4 < DT / 4; ++dd4) {
                    float4 xa[4];
                    #pragma unroll
                    for (int ti = 0; ti < 4; ++ti)
                        xa[ti] = *(const float4*)&xs[(tgrp * 4 + ti) * XS + h * D_ + dd0 + 4 * dd4];
                    #pragma unroll
                    for (int ki = 0; ki < 4; ++ki) {
                        const int code = kgrp + 32 * ki;
                        const int g = dd4 ^ (code & 7);
                        const float4 ca = *(const float4*)&cbs[code * DT + 4 * g];
                        #pragma unroll
                        for (int ti = 0; ti < 4; ++ti)
                            acc[ti][ki] += xa[ti].x * ca.x + xa[ti].y * ca.y
                                         + xa[ti].z * ca.z + xa[ti].w * ca.w;
                    }
                }
            }
            // fold chunk into running argmin (codes ascending within thread)
            #pragma unroll
            for (int ki = 0; ki < 4; ++ki) {
                const int code = k0 + kgrp + 32 * ki;
                const float cn = cnorm[h * K_ + code];
                #pragma unroll
                for (int ti = 0; ti < 4; ++ti) {
                    const float d = cn - 2.f * acc[ti][ki];
                    if (d < minv[ti]) { minv[ti] = d; mink[ti] = code; }
                }
            }
        }
        // cross-thread argmin reduce (lexicographic: value, then smaller k)
        #pragma unroll
        for (int ti = 0; ti < 4; ++ti) {
            rminv[tgrp * 4 + ti][kgrp] = minv[ti];
            rmink[tgrp * 4 + ti][kgrp] = mink[ti];
        }
        __syncthreads();
        if (tid < TT) {
            float bv = rminv[tid][0]; int bk = rmink[tid][0];
            for (int j = 1; j < 32; ++j) {
                const float v = rminv[tid][j]; const int k2 = rmink[tid][j];
                if (v < bv || (v == bv && k2 < bk)) { bv = v; bk = k2; }
            }
            idx_sh[tid][h] = bk;
        }
        __syncthreads();
    }

    // ---- histogram of overall indices ----
    if (tid < TT) {
        const int overall = idx_sh[tid][0] + K_ * idx_sh[tid][1];
        atomicAdd(&counts[overall], 1);
    }

    // ---- epilogue: gather codebook rows -> out, commit loss ----
    float csum = 0.f;
    {
        const int tt = tid & 31;
        int cc = tid >> 5;
        float* op = out + (size_t)n * C_ * T_ + t0 + tt;
        const int i0 = idx_sh[tt][0], i1 = idx_sh[tt][1];
        #pragma unroll 4
        for (int i = 0; i < C_ / 8; ++i, cc += 8) {
            const int h  = cc >> 8;
            const int dd = cc & 255;
            const int code = h ? i1 : i0;
            const float v = cb[((size_t)((h << 9) + code)) * D_ + dd];
            op[(size_t)cc * T_] = v;
            const float dx = xs[tt * XS + cc] - v;
            csum += dx * dx;
        }
    }
    for (int off = 32; off; off >>= 1) csum += __shfl_down(csum, off, 64);
    if ((tid & 63) == 0) wred[tid >> 6] = csum;
    __syncthreads();
    if (tid == 0) atomicAdd(commit, wred[0] + wred[1] + wred[2] + wred[3]);
}

// ---------------- kernel 3: scalars ----------------
__global__ void finalize_k(const int* __restrict__ counts,
                           const float* __restrict__ commit,
                           float* __restrict__ outsc)
{
    __shared__ float red[256];
    float s = 0.f;
    for (int i = threadIdx.x; i < NBINS; i += 256) {
        const float p = (float)counts[i] * (1.f / 65536.f);
        s += p * logf(p + 1e-7f);
    }
    red[threadIdx.x] = s;
    __syncthreads();
    for (int st = 128; st; st >>= 1) {
        if (threadIdx.x < st) red[threadIdx.x] += red[threadIdx.x + st];
        __syncthreads();
    }
    if (threadIdx.x == 0) {
        outsc[0] = commit[0] * (1.f / 33554432.f);   // commit loss mean
        outsc[1] = expf(-red[0]);                     // perplexity
    }
}

extern "C" void kernel_launch(void* const* d_in, const int* in_sizes, int n_in,
                              void* d_out, int out_size, void* d_ws, size_t ws_size,
                              hipStream_t stream) {
    const float* x  = (const float*)d_in[0];   // [32, 512, 2048]
    const float* cb = (const float*)d_in[1];   // [2, 512, 256]
    float* out = (float*)d_out;                // 33554432 + 2 scalars

    int*   counts = (int*)d_ws;                          // 1 MB
    float* commit = (float*)((char*)d_ws + NBINS * 4);   // 1 float
    float* cnorm  = (float*)((char*)d_ws + NBINS * 4 + 256); // 1024 floats

    hipMemsetAsync(d_ws, 0, NBINS * 4 + 256, stream);
    cnorm_k<<<H_ * K_, 64, 0, stream>>>(cb, cnorm);
    vq_main<<<dim3(T_ / TT, N_), 256, 0, stream>>>(x, cb, cnorm, out, counts, commit);
    finalize_k<<<1, 256, 0, stream>>>(counts, commit, out + 33554432);
}

// Round 2
// 967.440 us; speedup vs baseline: 1.4801x; 1.4801x over previous
//
#include <hip/hip_runtime.h>

#define N_ 32
#define C_ 512
#define T_ 2048
#define H_ 2
#define K_ 512
#define D_ 256
#define TT 32            // t-tile per block
#define KC 128           // codes per LDS chunk
#define DT 64            // dims per LDS chunk
#define NBINS (K_ * K_)  // 262144
#define XSS 260          // xs row stride (floats): bank rotation on writes, 16B-aligned rows
#define CTS 129          // cbt row stride (floats): odd -> conflict-free b32 code-gather

// ---------------- kernel 1: codebook squared norms ----------------
__global__ void cnorm_k(const float* __restrict__ cb, float* __restrict__ cnorm) {
    int id = blockIdx.x;            // 0..1023  (h*512 + k)
    int lane = threadIdx.x;         // 64 threads
    const float* p = cb + (size_t)id * D_;
    float s = 0.f;
    for (int i = lane; i < D_; i += 64) { float v = p[i]; s += v * v; }
    for (int off = 32; off; off >>= 1) s += __shfl_down(s, off, 64);
    if (lane == 0) cnorm[id] = s;
}

// ---------------- kernel 2: per-head fused distance/argmin/gather/loss ----------------
__global__ __launch_bounds__(256) void vq_main(
    const float* __restrict__ x, const float* __restrict__ cb,
    const float* __restrict__ cnorm, float* __restrict__ out,
    int* __restrict__ idx_ws, float* __restrict__ commit)
{
    __shared__ float xs[TT * XSS];       // 33,280 B : x[t][d] for this head
    __shared__ float cbt[DT * CTS];      // 33,024 B : TRANSPOSED [dim][code]
    __shared__ int   idx_sh[TT];
    __shared__ float wred[4];

    const int tid  = threadIdx.x;
    const int n    = blockIdx.y;
    const int h    = blockIdx.z;
    const int t0   = blockIdx.x * TT;
    const int tt   = tid & 31;
    const int kgrp = tid & 31;   // 32 code-groups, 4 strided codes each
    const int tgrp = tid >> 5;   // 8 t-groups, 4 t each

    // ---- stage x tile for this head: [D][Ttile] -> xs[t][d] ----
    {
        const float* xp = x + (size_t)n * C_ * T_ + (size_t)(h * D_) * T_ + t0 + tt;
        int c = tid >> 5;
        #pragma unroll 8
        for (int i = 0; i < D_ / 8; ++i, c += 8)
            xs[tt * XSS + c] = xp[(size_t)c * T_];
    }

    float minv[4]; int mink[4];
    #pragma unroll
    for (int ti = 0; ti < 4; ++ti) { minv[ti] = 1e30f; mink[ti] = 0; }

    for (int kc = 0; kc < K_ / KC; ++kc) {
        const int k0 = kc * KC;
        float acc[4][4];
        #pragma unroll
        for (int ti = 0; ti < 4; ++ti)
            #pragma unroll
            for (int ki = 0; ki < 4; ++ki) acc[ti][ki] = 0.f;

        for (int ddt = 0; ddt < D_ / DT; ++ddt) {
            const int dd0 = ddt * DT;
            __syncthreads();   // protect cbt (and first use of xs)
            // stage cbt[d][code] transposed; scalar writes land 2-way max (free)
            {
                const int i  = tid & 15;       // float4 group within DT dims
                const int j0 = tid >> 4;       // code row base
                #pragma unroll
                for (int it = 0; it < 8; ++it) {
                    const int j = j0 + (it << 4);
                    const float4 v = *(const float4*)&cb[((size_t)(h * K_ + k0 + j)) * D_ + dd0 + 4 * i];
                    cbt[(4 * i + 0) * CTS + j] = v.x;
                    cbt[(4 * i + 1) * CTS + j] = v.y;
                    cbt[(4 * i + 2) * CTS + j] = v.z;
                    cbt[(4 * i + 3) * CTS + j] = v.w;
                }
            }
            __syncthreads();
            // register-blocked 4t x 4k FMA; xa = broadcast b128, ca = conflict-free b32
            #pragma unroll 4
            for (int dd4 = 0; dd4 < DT / 4; ++dd4) {
                float4 xa[4];
                #pragma unroll
                for (int ti = 0; ti < 4; ++ti)
                    xa[ti] = *(const float4*)&xs[(tgrp * 4 + ti) * XSS + dd0 + 4 * dd4];
                #pragma unroll
                for (int ki = 0; ki < 4; ++ki) {
                    const int code = kgrp + 32 * ki;
                    const float c0 = cbt[(4 * dd4 + 0) * CTS + code];
                    const float c1 = cbt[(4 * dd4 + 1) * CTS + code];
                    const float c2 = cbt[(4 * dd4 + 2) * CTS + code];
                    const float c3 = cbt[(4 * dd4 + 3) * CTS + code];
                    #pragma unroll
                    for (int ti = 0; ti < 4; ++ti)
                        acc[ti][ki] += xa[ti].x * c0 + xa[ti].y * c1
                                     + xa[ti].z * c2 + xa[ti].w * c3;
                }
            }
        }
        // fold chunk into running argmin (codes ascending in ki and kc: strict < keeps first)
        #pragma unroll
        for (int ki = 0; ki < 4; ++ki) {
            const int code = k0 + kgrp + 32 * ki;
            const float cn = cnorm[h * K_ + code];
            #pragma unroll
            for (int ti = 0; ti < 4; ++ti) {
                const float d = cn - 2.f * acc[ti][ki];
                if (d < minv[ti]) { minv[ti] = d; mink[ti] = code; }
            }
        }
    }

    // ---- cross-lane argmin over kgrp (lexicographic), half-wave butterfly ----
    #pragma unroll
    for (int m = 16; m >= 1; m >>= 1) {
        #pragma unroll
        for (int ti = 0; ti < 4; ++ti) {
            const float ov = __shfl_xor(minv[ti], m, 64);
            const int   ok = __shfl_xor(mink[ti], m, 64);
            if (ov < minv[ti] || (ov == minv[ti] && ok < mink[ti])) {
                minv[ti] = ov; mink[ti] = ok;
            }
        }
    }
    if (kgrp == 0) {
        #pragma unroll
        for (int ti = 0; ti < 4; ++ti) {
            const int t = tgrp * 4 + ti;
            idx_sh[t] = mink[ti];
            idx_ws[((size_t)n * T_ + t0 + t) * H_ + h] = mink[ti];
        }
    }
    __syncthreads();

    // ---- epilogue: gather codebook rows -> out (this head's columns), commit loss ----
    float csum = 0.f;
    {
        float* op = out + (size_t)n * C_ * T_ + (size_t)(h * D_) * T_ + t0 + tt;
        const int code = idx_sh[tt];
        const float* cp = cb + ((size_t)(h * K_ + code)) * D_;
        int dd = tid >> 5;
        #pragma unroll 8
        for (int i = 0; i < D_ / 8; ++i, dd += 8) {
            const float v = cp[dd];
            op[(size_t)dd * T_] = v;
            const float dx = xs[tt * XSS + dd] - v;
            csum += dx * dx;
        }
    }
    for (int off = 32; off; off >>= 1) csum += __shfl_down(csum, off, 64);
    if ((tid & 63) == 0) wred[tid >> 6] = csum;
    __syncthreads();
    if (tid == 0) atomicAdd(commit, wred[0] + wred[1] + wred[2] + wred[3]);
}

// ---------------- kernel 3: histogram of overall indices ----------------
__global__ void hist_k(const int* __restrict__ idx_ws, int* __restrict__ counts) {
    const int gid = blockIdx.x * 256 + threadIdx.x;   // 0..65535 = (n,t)
    const int i0 = idx_ws[(size_t)gid * H_ + 0];
    const int i1 = idx_ws[(size_t)gid * H_ + 1];
    atomicAdd(&counts[i0 + K_ * i1], 1);
}

// ---------------- kernel 4: scalars ----------------
__global__ void finalize_k(const int* __restrict__ counts,
                           const float* __restrict__ commit,
                           float* __restrict__ outsc)
{
    __shared__ float red[256];
    float s = 0.f;
    for (int i = threadIdx.x; i < NBINS; i += 256) {
        const float p = (float)counts[i] * (1.f / 65536.f);
        s += p * logf(p + 1e-7f);
    }
    red[threadIdx.x] = s;
    __syncthreads();
    for (int st = 128; st; st >>= 1) {
        if (threadIdx.x < st) red[threadIdx.x] += red[threadIdx.x + st];
        __syncthreads();
    }
    if (threadIdx.x == 0) {
        outsc[0] = commit[0] * (1.f / 33554432.f);   // commit loss mean
        outsc[1] = expf(-red[0]);                     // perplexity
    }
}

extern "C" void kernel_launch(void* const* d_in, const int* in_sizes, int n_in,
                              void* d_out, int out_size, void* d_ws, size_t ws_size,
                              hipStream_t stream) {
    const float* x  = (const float*)d_in[0];   // [32, 512, 2048]
    const float* cb = (const float*)d_in[1];   // [2, 512, 256]
    float* out = (float*)d_out;                // 33554432 + 2 scalars

    int*   counts = (int*)d_ws;                               // 1 MB
    float* commit = (float*)((char*)d_ws + NBINS * 4);        // 1 float
    float* cnorm  = (float*)((char*)d_ws + NBINS * 4 + 256);  // 1024 floats
    int*   idx_ws = (int*)((char*)d_ws + NBINS * 4 + 8192);   // 512 KB

    hipMemsetAsync(d_ws, 0, NBINS * 4 + 8192, stream);
    cnorm_k<<<H_ * K_, 64, 0, stream>>>(cb, cnorm);
    vq_main<<<dim3(T_ / TT, N_, H_), 256, 0, stream>>>(x, cb, cnorm, out, idx_ws, commit);
    hist_k<<<N_ * T_ / 256, 256, 0, stream>>>(idx_ws, counts);
    finalize_k<<<1, 256, 0, stream>>>(counts, commit, out + 33554432);
}

// Round 3
// 472.087 us; speedup vs baseline: 3.0332x; 2.0493x over previous
//
#include <hip/hip_runtime.h>

#define N_ 32
#define C_ 512
#define T_ 2048
#define H_ 2
#define K_ 512
#define D_ 256
#define NBINS (K_ * K_)
#define TT 64
#define DELTA 0.6f

typedef __bf16 bf16x8 __attribute__((ext_vector_type(8)));
typedef float f32x4 __attribute__((ext_vector_type(4)));

__device__ __forceinline__ unsigned short f2b(float f) {
    return __builtin_bit_cast(unsigned short, (__bf16)f);
}
__device__ __forceinline__ float bf2f(unsigned bits_lo16) {
    return __builtin_bit_cast(float, bits_lo16 << 16);
}

// ---------------- prep: bf16 codebook + norms (fp32 & bf16-domain) ----------------
__global__ void prep_k(const float* __restrict__ cb, float* __restrict__ cnorm,
                       float* __restrict__ cnb, unsigned short* __restrict__ cbb) {
    const int id = blockIdx.x;      // h*512 + k
    const int lane = threadIdx.x;   // 64
    const float4 v = *(const float4*)(cb + (size_t)id * D_ + lane * 4);
    __bf16 b0 = (__bf16)v.x, b1 = (__bf16)v.y, b2 = (__bf16)v.z, b3 = (__bf16)v.w;
    ushort4 uu;
    uu.x = __builtin_bit_cast(unsigned short, b0);
    uu.y = __builtin_bit_cast(unsigned short, b1);
    uu.z = __builtin_bit_cast(unsigned short, b2);
    uu.w = __builtin_bit_cast(unsigned short, b3);
    *(ushort4*)(cbb + (size_t)id * D_ + lane * 4) = uu;
    float f0 = (float)b0, f1 = (float)b1, f2 = (float)b2, f3 = (float)b3;
    float s32 = v.x * v.x + v.y * v.y + v.z * v.z + v.w * v.w;
    float sbb = f0 * f0 + f1 * f1 + f2 * f2 + f3 * f3;
    #pragma unroll
    for (int m = 1; m <= 32; m <<= 1) {
        s32 += __shfl_xor(s32, m, 64);
        sbb += __shfl_xor(sbb, m, 64);
    }
    if (lane == 0) { cnorm[id] = s32; cnb[id] = sbb; }
}

// ---------------- main: MFMA distances + guarded exact argmin + gather/loss ----------------
__global__ __launch_bounds__(256, 2) void vq_main(
    const float* __restrict__ x, const float* __restrict__ cbf,
    const float* __restrict__ cnorm, const float* __restrict__ cnb,
    const unsigned short* __restrict__ cbb,
    float* __restrict__ out, int* __restrict__ idx_ws, float* __restrict__ commit)
{
    // LDS layout (bytes):
    // [0, 32768)            xsb: bf16 x-tile [64 t][256 d], row 512B, byte ^= ((t&7)<<4)
    // [32768, 66048)        cbs: dbuf 2x16KB (32 codes x 512B, swizzled)  /  win: [32][260] f32
    // [66048, 70144)        xrw: [4 waves][256] f32 rescue row
    // [70144, 70400)        idx_sh[64]
    // [70400, 70416)        wred[4]
    // [70416, 70736)        rl[4][20]
    __shared__ __align__(16) unsigned char SM[70736];
    unsigned short* xsb = (unsigned short*)SM;
    unsigned char*  cbs = SM + 32768;
    float* win   = (float*)(SM + 32768);
    float* xrw   = (float*)(SM + 66048);
    int*   idx_sh = (int*)(SM + 70144);
    float* wred  = (float*)(SM + 70400);
    int*   rl    = (int*)(SM + 70416);

    const int tid = threadIdx.x;
    const int lane = tid & 63;
    const int w = tid >> 6;
    const int n = blockIdx.y, h = blockIdx.z;
    const int t0 = blockIdx.x * TT;
    const size_t xbase = (size_t)n * C_ * T_ + (size_t)h * D_ * T_;

    // ---- issue codebook chunk 0 loads (reg staging) ----
    const uint4* cbb4 = (const uint4*)(cbb + (size_t)(h * K_) * D_);
    uint4 creg[4];
    {
        const int sb0 = w * 4096 + lane * 16;
        #pragma unroll
        for (int it = 0; it < 4; ++it)
            creg[it] = cbb4[(sb0 + it * 1024) >> 4];
    }

    // ---- transpose-stage x tile -> xsb (bf16, swizzled) via 4x4 shuffle transpose ----
    {
        const int tq = lane & 15, dl = lane >> 4;
        const float* xp = x + xbase + (size_t)(w * 64 + dl) * T_ + t0 + 4 * tq;
        const int t = 4 * tq + dl;
        #pragma unroll
        for (int i = 0; i < 16; ++i) {
            float4 v = *(const float4*)(xp + (size_t)(4 * i) * T_);
            float a0 = v.x, a1 = v.y, a2 = v.z, a3 = v.w;
            { float s = (lane & 16) ? a0 : a1; s = __shfl_xor(s, 16, 64); if (lane & 16) a0 = s; else a1 = s; }
            { float s = (lane & 16) ? a2 : a3; s = __shfl_xor(s, 16, 64); if (lane & 16) a2 = s; else a3 = s; }
            { float s = (lane & 32) ? a0 : a2; s = __shfl_xor(s, 32, 64); if (lane & 32) a0 = s; else a2 = s; }
            { float s = (lane & 32) ? a1 : a3; s = __shfl_xor(s, 32, 64); if (lane & 32) a1 = s; else a3 = s; }
            // a_j = x[t][w*64 + 4*i + j]
            uint2 pk;
            pk.x = (unsigned)f2b(a0) | ((unsigned)f2b(a1) << 16);
            pk.y = (unsigned)f2b(a2) | ((unsigned)f2b(a3) << 16);
            const int off = (w * 64 + 4 * i) * 2;
            *(uint2*)((unsigned char*)xsb + t * 512 + (off ^ ((t & 7) << 4))) = pk;
        }
    }

    // ---- write codebook chunk 0 into LDS (swizzled) ----
    #pragma unroll
    for (int it = 0; it < 4; ++it) {
        const int sb = w * 4096 + it * 1024 + lane * 16;
        const int code = sb >> 9, off = sb & 511;
        *(uint4*)(cbs + code * 512 + (off ^ ((code & 7) << 4))) = creg[it];
    }
    __syncthreads();

    // ---- A fragments (this wave's 16 t rows) ----
    uint4 au[8];
    const int tA = 16 * w + (lane & 15);
    const int koff = (lane >> 4) * 16;     // byte offset of k-slice
    #pragma unroll
    for (int kt = 0; kt < 8; ++kt) {
        const int off = kt * 64 + koff;
        au[kt] = *(const uint4*)((unsigned char*)xsb + tA * 512 + (off ^ ((tA & 7) << 4)));
    }

    // ---- chunk loop: 16 chunks x 32 codes ----
    float m1[4], m2[4]; int k1[4];
    #pragma unroll
    for (int q = 0; q < 4; ++q) { m1[q] = 3e38f; m2[q] = 3e38f; k1[q] = 0; }
    unsigned d2s[32][2];
    const int col = lane & 15;

    #pragma unroll
    for (int kc = 0; kc < 16; ++kc) {
        const int buf = (kc & 1) * 16384;
        if (kc < 15) {
            const int sb0 = w * 4096 + lane * 16;
            #pragma unroll
            for (int it = 0; it < 4; ++it)
                creg[it] = cbb4[((kc + 1) * 16384 + sb0 + it * 1024) >> 4];
        }
        const float cn0 = cnb[h * K_ + kc * 32 + col];
        const float cn1 = cnb[h * K_ + kc * 32 + 16 + col];

        #pragma unroll
        for (int sub = 0; sub < 2; ++sub) {
            const int c32 = sub * 16 + col;
            f32x4 acc = {0.f, 0.f, 0.f, 0.f};
            #pragma unroll
            for (int kt = 0; kt < 8; ++kt) {
                uint4 bu = *(const uint4*)(cbs + buf + c32 * 512 + ((kt * 64 + koff) ^ ((c32 & 7) << 4)));
                acc = __builtin_amdgcn_mfma_f32_16x16x32_bf16(
                        __builtin_bit_cast(bf16x8, au[kt]),
                        __builtin_bit_cast(bf16x8, bu), acc, 0, 0, 0);
            }
            const float cn = sub ? cn1 : cn0;
            const int code = kc * 32 + sub * 16 + col;
            float d2q[4];
            #pragma unroll
            for (int q = 0; q < 4; ++q) {
                const float d = fmaf(-2.f, acc[q], cn);
                d2q[q] = d;
                const float mx = fmaxf(d, m1[q]);
                m2[q] = fminf(m2[q], mx);
                const bool lt = d < m1[q];
                k1[q] = lt ? code : k1[q];
                m1[q] = lt ? d : m1[q];
            }
            d2s[kc * 2 + sub][0] = (unsigned)f2b(d2q[0]) | ((unsigned)f2b(d2q[1]) << 16);
            d2s[kc * 2 + sub][1] = (unsigned)f2b(d2q[2]) | ((unsigned)f2b(d2q[3]) << 16);
        }
        if (kc < 15) {
            #pragma unroll
            for (int it = 0; it < 4; ++it) {
                const int sb = w * 4096 + it * 1024 + lane * 16;
                const int code = sb >> 9, off = sb & 511;
                *(uint4*)(cbs + (buf ^ 16384) + code * 512 + (off ^ ((code & 7) << 4))) = creg[it];
            }
        }
        __syncthreads();
    }

    // ---- cross-lane (16 cols) lexicographic argmin + global 2nd-min ----
    #pragma unroll
    for (int m = 1; m <= 8; m <<= 1) {
        #pragma unroll
        for (int q = 0; q < 4; ++q) {
            const float om1 = __shfl_xor(m1[q], m, 64);
            const int   ok  = __shfl_xor(k1[q], m, 64);
            const float om2 = __shfl_xor(m2[q], m, 64);
            const float nm2 = fminf(fminf(m2[q], om2), fmaxf(m1[q], om1));
            const bool sw = (om1 < m1[q]) || (om1 == m1[q] && ok < k1[q]);
            m1[q] = sw ? om1 : m1[q];
            k1[q] = sw ? ok : k1[q];
            m2[q] = nm2;
        }
    }

    if (lane == 0) rl[w * 20] = 0;
    const int g = lane >> 4;

    // ---- guarded exact rescore (rare) ----
    #pragma unroll
    for (int gg = 0; gg < 4; ++gg) {
        #pragma unroll
        for (int q = 0; q < 4; ++q) {
            const float bm1 = __shfl(m1[q], gg << 4, 64);
            const float bm2 = __shfl(m2[q], gg << 4, 64);
            if (bm2 < bm1 + DELTA) {
                const int row = 16 * w + 4 * gg + q;
                const float* xc = x + xbase + t0 + row;
                float4 xr;
                xr.x = xc[(size_t)(lane * 4 + 0) * T_];
                xr.y = xc[(size_t)(lane * 4 + 1) * T_];
                xr.z = xc[(size_t)(lane * 4 + 2) * T_];
                xr.w = xc[(size_t)(lane * 4 + 3) * T_];
                *(float4*)&xrw[w * 256 + lane * 4] = xr;
                if (g == gg) {
                    const float thrw = bm1 + (DELTA + 1.5f);
                    #pragma unroll
                    for (int i = 0; i < 32; ++i) {
                        const unsigned uu = d2s[i][q >> 1];
                        const float s = (q & 1) ? __builtin_bit_cast(float, uu & 0xffff0000u)
                                                : __builtin_bit_cast(float, uu << 16);
                        if (s < thrw) {
                            const int pos = atomicAdd(&rl[w * 20], 1);
                            if (pos < 19) rl[w * 20 + 1 + pos] = i * 16 + col;
                        }
                    }
                }
                __asm__ volatile("s_waitcnt lgkmcnt(0)" ::: "memory");
                int nc = rl[w * 20];
                if (nc > 19) nc = 19;
                float bv = 3e38f; int bk = 0x7fffffff;
                for (int ci = 0; ci < nc; ++ci) {
                    const int code = rl[w * 20 + 1 + ci];
                    const float4 xv = *(const float4*)&xrw[w * 256 + lane * 4];
                    const float4 cv = *(const float4*)&cbf[(size_t)(h * K_ + code) * D_ + lane * 4];
                    float d = xv.x * cv.x + xv.y * cv.y + xv.z * cv.z + xv.w * cv.w;
                    #pragma unroll
                    for (int mm = 1; mm <= 32; mm <<= 1) d += __shfl_xor(d, mm, 64);
                    const float d2x = cnorm[h * K_ + code] - 2.f * d;
                    if (d2x < bv || (d2x == bv && code < bk)) { bv = d2x; bk = code; }
                }
                if (g == gg) k1[q] = bk;
                if (lane == 0) rl[w * 20] = 0;
            }
        }
    }

    // ---- write indices ----
    if ((lane & 15) == 0) {
        #pragma unroll
        for (int q = 0; q < 4; ++q) {
            const int row = 16 * w + 4 * g + q;
            idx_sh[row] = k1[q];
            idx_ws[((size_t)n * T_ + t0 + row) * H_ + h] = k1[q];
        }
    }
    __syncthreads();

    // ---- epilogue: gather winners via LDS, out write, commit loss ----
    float csum = 0.f;
    #pragma unroll
    for (int ch = 0; ch < 2; ++ch) {
        #pragma unroll
        for (int rr = 0; rr < 8; ++rr) {
            const int row = ch * 32 + w * 8 + rr;
            const int code = idx_sh[row];
            const float4 cv = *(const float4*)&cbf[(size_t)(h * K_ + code) * D_ + lane * 4];
            const int off = (8 * lane) ^ ((row & 7) << 4);
            const uint2 pk = *(const uint2*)((unsigned char*)xsb + row * 512 + off);
            const float x0 = bf2f(pk.x & 0xffffu), x1 = bf2f(pk.x >> 16);
            const float x2 = bf2f(pk.y & 0xffffu), x3 = bf2f(pk.y >> 16);
            const float e0 = x0 - cv.x, e1 = x1 - cv.y, e2 = x2 - cv.z, e3 = x3 - cv.w;
            csum += e0 * e0 + e1 * e1 + e2 * e2 + e3 * e3;
            *(float4*)&win[(row & 31) * 260 + lane * 4] = cv;
        }
        __syncthreads();
        const int t32 = tid & 31, cg = tid >> 5;
        float* op = out + (size_t)n * C_ * T_ + (size_t)h * D_ * T_ + t0 + ch * 32 + t32;
        #pragma unroll
        for (int i = 0; i < 32; ++i) {
            const int c = cg + 8 * i;
            op[(size_t)c * T_] = win[t32 * 260 + c];
        }
        __syncthreads();
    }
    #pragma unroll
    for (int mm = 1; mm <= 32; mm <<= 1) csum += __shfl_xor(csum, mm, 64);
    if (lane == 0) wred[w] = csum;
    __syncthreads();
    if (tid == 0) atomicAdd(commit, wred[0] + wred[1] + wred[2] + wred[3]);
}

// ---------------- histogram ----------------
__global__ void hist_k(const int* __restrict__ idx_ws, int* __restrict__ counts) {
    const int gid = blockIdx.x * 256 + threadIdx.x;
    const int i0 = idx_ws[(size_t)gid * H_ + 0];
    const int i1 = idx_ws[(size_t)gid * H_ + 1];
    atomicAdd(&counts[i0 + K_ * i1], 1);
}

// ---------------- scalars ----------------
__global__ void finalize_k(const int* __restrict__ counts,
                           const float* __restrict__ commit,
                           float* __restrict__ outsc)
{
    __shared__ float red[256];
    float s = 0.f;
    for (int i = threadIdx.x; i < NBINS; i += 256) {
        const float p = (float)counts[i] * (1.f / 65536.f);
        s += p * logf(p + 1e-7f);
    }
    red[threadIdx.x] = s;
    __syncthreads();
    for (int st = 128; st; st >>= 1) {
        if (threadIdx.x < st) red[threadIdx.x] += red[threadIdx.x + st];
        __syncthreads();
    }
    if (threadIdx.x == 0) {
        outsc[0] = commit[0] * (1.f / 33554432.f);
        outsc[1] = expf(-red[0]);
    }
}

extern "C" void kernel_launch(void* const* d_in, const int* in_sizes, int n_in,
                              void* d_out, int out_size, void* d_ws, size_t ws_size,
                              hipStream_t stream) {
    const float* x  = (const float*)d_in[0];   // [32, 512, 2048]
    const float* cb = (const float*)d_in[1];   // [2, 512, 256]
    float* out = (float*)d_out;

    char* ws = (char*)d_ws;
    int*   counts = (int*)ws;                              // 1 MB
    float* commit = (float*)(ws + 1048576);
    float* cnorm  = (float*)(ws + 1048832);                // 1024 f32
    float* cnb    = (float*)(ws + 1052928);                // 1024 f32
    unsigned short* cbb = (unsigned short*)(ws + 1057024); // 512 KB bf16 codebook
    int*   idx_ws = (int*)(ws + 1581312);                  // 512 KB

    hipMemsetAsync(d_ws, 0, 1048832, stream);
    prep_k<<<H_ * K_, 64, 0, stream>>>(cb, cnorm, cnb, cbb);
    vq_main<<<dim3(T_ / TT, N_, H_), 256, 0, stream>>>(x, cb, cnorm, cnb, cbb, out, idx_ws, commit);
    hist_k<<<N_ * T_ / 256, 256, 0, stream>>>(idx_ws, counts);
    finalize_k<<<1, 256, 0, stream>>>(counts, commit, out + 33554432);
}

// Round 4
// 151.920 us; speedup vs baseline: 9.4257x; 3.1075x over previous
//
#include <hip/hip_runtime.h>

#define N_ 32
#define C_ 512
#define T_ 2048
#define H_ 2
#define K_ 512
#define D_ 256
#define NBINS (K_ * K_)
#define TT 64
#define DELTA 0.6f

typedef __bf16 bf16x8 __attribute__((ext_vector_type(8)));
typedef float f32x4 __attribute__((ext_vector_type(4)));

__device__ __forceinline__ unsigned short f2b(float f) {
    return __builtin_bit_cast(unsigned short, (__bf16)f);
}
__device__ __forceinline__ float bf2f(unsigned bits_lo16) {
    return __builtin_bit_cast(float, bits_lo16 << 16);
}

// ---------------- prep: bf16 codebook + norms (fp32 & bf16-domain) ----------------
__global__ void prep_k(const float* __restrict__ cb, float* __restrict__ cnorm,
                       float* __restrict__ cnb, unsigned short* __restrict__ cbb) {
    const int id = blockIdx.x;      // h*512 + k
    const int lane = threadIdx.x;   // 64
    const float4 v = *(const float4*)(cb + (size_t)id * D_ + lane * 4);
    __bf16 b0 = (__bf16)v.x, b1 = (__bf16)v.y, b2 = (__bf16)v.z, b3 = (__bf16)v.w;
    ushort4 uu;
    uu.x = __builtin_bit_cast(unsigned short, b0);
    uu.y = __builtin_bit_cast(unsigned short, b1);
    uu.z = __builtin_bit_cast(unsigned short, b2);
    uu.w = __builtin_bit_cast(unsigned short, b3);
    *(ushort4*)(cbb + (size_t)id * D_ + lane * 4) = uu;
    float f0 = (float)b0, f1 = (float)b1, f2 = (float)b2, f3 = (float)b3;
    float s32 = v.x * v.x + v.y * v.y + v.z * v.z + v.w * v.w;
    float sbb = f0 * f0 + f1 * f1 + f2 * f2 + f3 * f3;
    #pragma unroll
    for (int m = 1; m <= 32; m <<= 1) {
        s32 += __shfl_xor(s32, m, 64);
        sbb += __shfl_xor(sbb, m, 64);
    }
    if (lane == 0) { cnorm[id] = s32; cnb[id] = sbb; }
}

// ---------------- main: MFMA distances + guarded exact argmin + gather/loss ----------------
__global__ __launch_bounds__(256, 2) void vq_main(
    const float* __restrict__ x, const float* __restrict__ cbf,
    const float* __restrict__ cnorm, const float* __restrict__ cnb,
    const unsigned short* __restrict__ cbb,
    float* __restrict__ out, int* __restrict__ idx_ws, float* __restrict__ commit)
{
    // LDS layout (bytes):
    // [0, 32768)            xsb: bf16 x-tile [64 t][256 d], row 512B, byte ^= ((t&7)<<4)
    // [32768, 66048)        cbs: dbuf 2x16KB (32 codes x 512B, swizzled)  /  win: [32][260] f32
    // [66048, 70144)        xrw: [4 waves][256] f32 rescue row
    // [70144, 70400)        idx_sh[64]
    // [70400, 70416)        wred[4]
    // [70416, 70736)        rl[4][20]
    __shared__ __align__(16) unsigned char SM[70736];
    unsigned short* xsb = (unsigned short*)SM;
    unsigned char*  cbs = SM + 32768;
    float* win   = (float*)(SM + 32768);
    float* xrw   = (float*)(SM + 66048);
    int*   idx_sh = (int*)(SM + 70144);
    float* wred  = (float*)(SM + 70400);
    int*   rl    = (int*)(SM + 70416);

    const int tid = threadIdx.x;
    const int lane = tid & 63;
    const int w = tid >> 6;
    const int n = blockIdx.y, h = blockIdx.z;
    const int t0 = blockIdx.x * TT;
    const size_t xbase = (size_t)n * C_ * T_ + (size_t)h * D_ * T_;

    // ---- issue codebook chunk 0 loads (reg staging) ----
    const uint4* cbb4 = (const uint4*)(cbb + (size_t)(h * K_) * D_);
    uint4 creg[4];
    {
        const int sb0 = w * 4096 + lane * 16;
        #pragma unroll
        for (int it = 0; it < 4; ++it)
            creg[it] = cbb4[(sb0 + it * 1024) >> 4];
    }

    // ---- transpose-stage x tile -> xsb (bf16, swizzled) via 4x4 shuffle transpose ----
    {
        const int tq = lane & 15, dl = lane >> 4;
        const float* xp = x + xbase + (size_t)(w * 64 + dl) * T_ + t0 + 4 * tq;
        const int t = 4 * tq + dl;
        #pragma unroll
        for (int i = 0; i < 16; ++i) {
            float4 v = *(const float4*)(xp + (size_t)(4 * i) * T_);
            float a0 = v.x, a1 = v.y, a2 = v.z, a3 = v.w;
            { float s = (lane & 16) ? a0 : a1; s = __shfl_xor(s, 16, 64); if (lane & 16) a0 = s; else a1 = s; }
            { float s = (lane & 16) ? a2 : a3; s = __shfl_xor(s, 16, 64); if (lane & 16) a2 = s; else a3 = s; }
            { float s = (lane & 32) ? a0 : a2; s = __shfl_xor(s, 32, 64); if (lane & 32) a0 = s; else a2 = s; }
            { float s = (lane & 32) ? a1 : a3; s = __shfl_xor(s, 32, 64); if (lane & 32) a1 = s; else a3 = s; }
            // a_j = x[t][w*64 + 4*i + j]
            uint2 pk;
            pk.x = (unsigned)f2b(a0) | ((unsigned)f2b(a1) << 16);
            pk.y = (unsigned)f2b(a2) | ((unsigned)f2b(a3) << 16);
            const int off = (w * 64 + 4 * i) * 2;
            *(uint2*)((unsigned char*)xsb + t * 512 + (off ^ ((t & 7) << 4))) = pk;
        }
    }

    // ---- write codebook chunk 0 into LDS (swizzled) ----
    #pragma unroll
    for (int it = 0; it < 4; ++it) {
        const int sb = w * 4096 + it * 1024 + lane * 16;
        const int code = sb >> 9, off = sb & 511;
        *(uint4*)(cbs + code * 512 + (off ^ ((code & 7) << 4))) = creg[it];
    }
    __syncthreads();

    // ---- A fragments (this wave's 16 t rows) ----
    uint4 au[8];
    const int tA = 16 * w + (lane & 15);
    const int koff = (lane >> 4) * 16;     // byte offset of k-slice
    #pragma unroll
    for (int kt = 0; kt < 8; ++kt) {
        const int off = kt * 64 + koff;
        au[kt] = *(const uint4*)((unsigned char*)xsb + tA * 512 + (off ^ ((tA & 7) << 4)));
    }

    // ---- chunk loop: 16 chunks x 32 codes ----
    float m1[4], m2[4]; int k1[4];
    #pragma unroll
    for (int q = 0; q < 4; ++q) { m1[q] = 3e38f; m2[q] = 3e38f; k1[q] = 0; }
    unsigned d2s[32][2];
    const int col = lane & 15;

    #pragma unroll
    for (int kc = 0; kc < 16; ++kc) {
        const int buf = (kc & 1) * 16384;
        if (kc < 15) {
            const int sb0 = w * 4096 + lane * 16;
            #pragma unroll
            for (int it = 0; it < 4; ++it)
                creg[it] = cbb4[((kc + 1) * 16384 + sb0 + it * 1024) >> 4];
        }
        const float cn0 = cnb[h * K_ + kc * 32 + col];
        const float cn1 = cnb[h * K_ + kc * 32 + 16 + col];

        #pragma unroll
        for (int sub = 0; sub < 2; ++sub) {
            const int c32 = sub * 16 + col;
            f32x4 acc = {0.f, 0.f, 0.f, 0.f};
            #pragma unroll
            for (int kt = 0; kt < 8; ++kt) {
                uint4 bu = *(const uint4*)(cbs + buf + c32 * 512 + ((kt * 64 + koff) ^ ((c32 & 7) << 4)));
                acc = __builtin_amdgcn_mfma_f32_16x16x32_bf16(
                        __builtin_bit_cast(bf16x8, au[kt]),
                        __builtin_bit_cast(bf16x8, bu), acc, 0, 0, 0);
            }
            const float cn = sub ? cn1 : cn0;
            const int code = kc * 32 + sub * 16 + col;
            float d2q[4];
            #pragma unroll
            for (int q = 0; q < 4; ++q) {
                const float d = fmaf(-2.f, acc[q], cn);
                d2q[q] = d;
                const float mx = fmaxf(d, m1[q]);
                m2[q] = fminf(m2[q], mx);
                const bool lt = d < m1[q];
                k1[q] = lt ? code : k1[q];
                m1[q] = lt ? d : m1[q];
            }
            d2s[kc * 2 + sub][0] = (unsigned)f2b(d2q[0]) | ((unsigned)f2b(d2q[1]) << 16);
            d2s[kc * 2 + sub][1] = (unsigned)f2b(d2q[2]) | ((unsigned)f2b(d2q[3]) << 16);
        }
        if (kc < 15) {
            #pragma unroll
            for (int it = 0; it < 4; ++it) {
                const int sb = w * 4096 + it * 1024 + lane * 16;
                const int code = sb >> 9, off = sb & 511;
                *(uint4*)(cbs + (buf ^ 16384) + code * 512 + (off ^ ((code & 7) << 4))) = creg[it];
            }
        }
        __syncthreads();
    }

    // ---- cross-lane (16 cols) lexicographic argmin + global 2nd-min ----
    #pragma unroll
    for (int m = 1; m <= 8; m <<= 1) {
        #pragma unroll
        for (int q = 0; q < 4; ++q) {
            const float om1 = __shfl_xor(m1[q], m, 64);
            const int   ok  = __shfl_xor(k1[q], m, 64);
            const float om2 = __shfl_xor(m2[q], m, 64);
            const float nm2 = fminf(fminf(m2[q], om2), fmaxf(m1[q], om1));
            const bool sw = (om1 < m1[q]) || (om1 == m1[q] && ok < k1[q]);
            m1[q] = sw ? om1 : m1[q];
            k1[q] = sw ? ok : k1[q];
            m2[q] = nm2;
        }
    }

    if (lane == 0) rl[w * 20] = 0;
    const int g = lane >> 4;

    // ---- guarded exact rescore (rare) ----
    #pragma unroll
    for (int gg = 0; gg < 4; ++gg) {
        #pragma unroll
        for (int q = 0; q < 4; ++q) {
            const float bm1 = __shfl(m1[q], gg << 4, 64);
            const float bm2 = __shfl(m2[q], gg << 4, 64);
            if (bm2 < bm1 + DELTA) {
                const int row = 16 * w + 4 * gg + q;
                const float* xc = x + xbase + t0 + row;
                float4 xr;
                xr.x = xc[(size_t)(lane * 4 + 0) * T_];
                xr.y = xc[(size_t)(lane * 4 + 1) * T_];
                xr.z = xc[(size_t)(lane * 4 + 2) * T_];
                xr.w = xc[(size_t)(lane * 4 + 3) * T_];
                *(float4*)&xrw[w * 256 + lane * 4] = xr;
                if (g == gg) {
                    const float thrw = bm1 + (DELTA + 1.5f);
                    #pragma unroll
                    for (int i = 0; i < 32; ++i) {
                        const unsigned uu = d2s[i][q >> 1];
                        const float s = (q & 1) ? __builtin_bit_cast(float, uu & 0xffff0000u)
                                                : __builtin_bit_cast(float, uu << 16);
                        if (s < thrw) {
                            const int pos = atomicAdd(&rl[w * 20], 1);
                            if (pos < 19) rl[w * 20 + 1 + pos] = i * 16 + col;
                        }
                    }
                }
                __asm__ volatile("s_waitcnt lgkmcnt(0)" ::: "memory");
                int nc = rl[w * 20];
                if (nc > 19) nc = 19;
                float bv = 3e38f; int bk = 0x7fffffff;
                for (int ci = 0; ci < nc; ++ci) {
                    const int code = rl[w * 20 + 1 + ci];
                    const float4 xv = *(const float4*)&xrw[w * 256 + lane * 4];
                    const float4 cv = *(const float4*)&cbf[(size_t)(h * K_ + code) * D_ + lane * 4];
                    float d = xv.x * cv.x + xv.y * cv.y + xv.z * cv.z + xv.w * cv.w;
                    #pragma unroll
                    for (int mm = 1; mm <= 32; mm <<= 1) d += __shfl_xor(d, mm, 64);
                    const float d2x = cnorm[h * K_ + code] - 2.f * d;
                    if (d2x < bv || (d2x == bv && code < bk)) { bv = d2x; bk = code; }
                }
                if (g == gg) k1[q] = bk;
                if (lane == 0) rl[w * 20] = 0;
            }
        }
    }

    // ---- write indices ----
    if ((lane & 15) == 0) {
        #pragma unroll
        for (int q = 0; q < 4; ++q) {
            const int row = 16 * w + 4 * g + q;
            idx_sh[row] = k1[q];
            idx_ws[((size_t)n * T_ + t0 + row) * H_ + h] = k1[q];
        }
    }
    __syncthreads();

    // ---- epilogue: gather winners via LDS, out write, commit loss ----
    float csum = 0.f;
    #pragma unroll
    for (int ch = 0; ch < 2; ++ch) {
        #pragma unroll
        for (int rr = 0; rr < 8; ++rr) {
            const int row = ch * 32 + w * 8 + rr;
            const int code = idx_sh[row];
            const float4 cv = *(const float4*)&cbf[(size_t)(h * K_ + code) * D_ + lane * 4];
            const int off = (8 * lane) ^ ((row & 7) << 4);
            const uint2 pk = *(const uint2*)((unsigned char*)xsb + row * 512 + off);
            const float x0 = bf2f(pk.x & 0xffffu), x1 = bf2f(pk.x >> 16);
            const float x2 = bf2f(pk.y & 0xffffu), x3 = bf2f(pk.y >> 16);
            const float e0 = x0 - cv.x, e1 = x1 - cv.y, e2 = x2 - cv.z, e3 = x3 - cv.w;
            csum += e0 * e0 + e1 * e1 + e2 * e2 + e3 * e3;
            *(float4*)&win[(row & 31) * 260 + lane * 4] = cv;
        }
        __syncthreads();
        const int t32 = tid & 31, cg = tid >> 5;
        float* op = out + (size_t)n * C_ * T_ + (size_t)h * D_ * T_ + t0 + ch * 32 + t32;
        #pragma unroll
        for (int i = 0; i < 32; ++i) {
            const int c = cg + 8 * i;
            op[(size_t)c * T_] = win[t32 * 260 + c];
        }
        __syncthreads();
    }
    #pragma unroll
    for (int mm = 1; mm <= 32; mm <<= 1) csum += __shfl_xor(csum, mm, 64);
    if (lane == 0) wred[w] = csum;
    __syncthreads();
    if (tid == 0) atomicAdd(commit, wred[0] + wred[1] + wred[2] + wred[3]);
}

// ---------------- histogram ----------------
__global__ void hist_k(const int* __restrict__ idx_ws, int* __restrict__ counts) {
    const int gid = blockIdx.x * 256 + threadIdx.x;
    const int i0 = idx_ws[(size_t)gid * H_ + 0];
    const int i1 = idx_ws[(size_t)gid * H_ + 1];
    atomicAdd(&counts[i0 + K_ * i1], 1);
}

// ---------------- entropy: 256 blocks x 256 threads x int4 ----------------
__global__ __launch_bounds__(256) void entropy_k(const int* __restrict__ counts,
                                                 float* __restrict__ ent) {
    __shared__ float red[4];
    const int tid = threadIdx.x;
    const int4 c4 = *(const int4*)(counts + 4 * (blockIdx.x * 256 + tid));
    float s = 0.f;
    {
        const float p0 = (float)c4.x * (1.f / 65536.f);
        const float p1 = (float)c4.y * (1.f / 65536.f);
        const float p2 = (float)c4.z * (1.f / 65536.f);
        const float p3 = (float)c4.w * (1.f / 65536.f);
        s = p0 * logf(p0 + 1e-7f) + p1 * logf(p1 + 1e-7f)
          + p2 * logf(p2 + 1e-7f) + p3 * logf(p3 + 1e-7f);
    }
    #pragma unroll
    for (int m = 1; m <= 32; m <<= 1) s += __shfl_xor(s, m, 64);
    if ((tid & 63) == 0) red[tid >> 6] = s;
    __syncthreads();
    if (tid == 0) atomicAdd(ent, red[0] + red[1] + red[2] + red[3]);
}

// ---------------- scalars ----------------
__global__ void final_k(const float* __restrict__ ent,
                        const float* __restrict__ commit,
                        float* __restrict__ outsc) {
    if (threadIdx.x == 0) {
        outsc[0] = commit[0] * (1.f / 33554432.f);
        outsc[1] = expf(-ent[0]);
    }
}

extern "C" void kernel_launch(void* const* d_in, const int* in_sizes, int n_in,
                              void* d_out, int out_size, void* d_ws, size_t ws_size,
                              hipStream_t stream) {
    const float* x  = (const float*)d_in[0];   // [32, 512, 2048]
    const float* cb = (const float*)d_in[1];   // [2, 512, 256]
    float* out = (float*)d_out;

    char* ws = (char*)d_ws;
    int*   counts = (int*)ws;                              // 1 MB
    float* commit = (float*)(ws + 1048576);
    float* ent    = (float*)(ws + 1048580);
    float* cnorm  = (float*)(ws + 1048832);                // 1024 f32
    float* cnb    = (float*)(ws + 1052928);                // 1024 f32
    unsigned short* cbb = (unsigned short*)(ws + 1057024); // 512 KB bf16 codebook
    int*   idx_ws = (int*)(ws + 1581312);                  // 512 KB

    hipMemsetAsync(d_ws, 0, 1048832, stream);
    prep_k<<<H_ * K_, 64, 0, stream>>>(cb, cnorm, cnb, cbb);
    vq_main<<<dim3(T_ / TT, N_, H_), 256, 0, stream>>>(x, cb, cnorm, cnb, cbb, out, idx_ws, commit);
    hist_k<<<N_ * T_ / 256, 256, 0, stream>>>(idx_ws, counts);
    entropy_k<<<NBINS / 1024, 256, 0, stream>>>(counts, ent);
    final_k<<<1, 64, 0, stream>>>(ent, commit, out + 33554432);
}